// Round 9
// baseline (103.087 us; speedup 1.0000x reference)
//
#include <hip/hip_runtime.h>
#include <cfloat>

// BottomRightPool: out[b,c,i,j] = max(x[b,c,:i+1,:j+1])
//                = cummax over H then cummax over W.
//
// Formulation: out[i] = max(out[i-1], rowscan(x[i])) per column.
// One wave per 128x128 fp32 image (4096 waves). float4 per lane ->
// one 1 KiB instruction covers TWO rows: lanes 0..31 hold row 2k
// (4 cols/lane), lanes 32..63 hold row 2k+1.
//
// Cache policy (R8): input footprint (268 MB) == L3 capacity -> exact
// fit self-thrashes to ~50% hits (FETCH was exactly I/2). Partition:
// 13/16 of images use PLAIN cacheable loads (218 MB hot set, 19% slack
// -> stays resident across graph replays); 3/16 use NONTEMPORAL loads
// (streamed, evict-first, never pollute the hot set). All stores
// nontemporal so the output stream stays out of L3.

typedef float v4f __attribute__((ext_vector_type(4)));

template <bool NTLOAD>
__device__ __forceinline__ void process_image(const v4f* __restrict__ xi,
                                              v4f* __restrict__ oi,
                                              int lane, bool hi) {
    // Running column max for this lane's 4 columns, replicated in both halves.
    float cm0 = -FLT_MAX, cm1 = -FLT_MAX, cm2 = -FLT_MAX, cm3 = -FLT_MAX;

    #pragma unroll 4
    for (int k = 0; k < 64; ++k) {              // k covers rows 2k, 2k+1
        v4f v = NTLOAD ? __builtin_nontemporal_load(&xi[k * 64])
                       : xi[k * 64];

        // Per-lane inclusive prefixes over the 4 owned columns.
        float p0 = v.x;
        float p1 = fmaxf(p0, v.y);
        float p2 = fmaxf(p1, v.z);
        float p3 = fmaxf(p2, v.w);

        // 32-lane segmented inclusive max-scan of p3 (self-clamped shfl_up).
        float s = p3;
        s = fmaxf(s, __shfl_up(s, 1, 32));
        s = fmaxf(s, __shfl_up(s, 2, 32));
        s = fmaxf(s, __shfl_up(s, 4, 32));
        s = fmaxf(s, __shfl_up(s, 8, 32));
        s = fmaxf(s, __shfl_up(s, 16, 32));
        float e = __shfl_up(s, 1, 32);
        if ((lane & 31) == 0) e = -FLT_MAX;

        // Rowscan of this row at the 4 owned columns.
        float r0 = fmaxf(e, p0);
        float r1 = fmaxf(e, p1);
        float r2 = fmaxf(e, p2);
        float r3 = s;                            // == max(e, p3)

        // Combined two-row rowscan max (same in both halves).
        float t0 = fmaxf(r0, __shfl_xor(r0, 32));
        float t1 = fmaxf(r1, __shfl_xor(r1, 32));
        float t2 = fmaxf(r2, __shfl_xor(r2, 32));
        float t3 = fmaxf(r3, __shfl_xor(r3, 32));

        // Row 2k (lo lanes): out = max(cm, own-row scan);
        // Row 2k+1 (hi lanes): out = max(cm, both-row scan).
        v4f o;
        o.x = fmaxf(cm0, hi ? t0 : r0);
        o.y = fmaxf(cm1, hi ? t1 : r1);
        o.z = fmaxf(cm2, hi ? t2 : r2);
        o.w = fmaxf(cm3, hi ? t3 : r3);

        cm0 = fmaxf(cm0, t0);
        cm1 = fmaxf(cm1, t1);
        cm2 = fmaxf(cm2, t2);
        cm3 = fmaxf(cm3, t3);

        __builtin_nontemporal_store(o, &oi[k * 64]);
    }
}

__global__ __launch_bounds__(64)
void BottomRightPool_54357106098213_kernel(const float* __restrict__ x,
                                           float* __restrict__ out) {
    const size_t img = blockIdx.x;              // b*256 + c
    const int lane = threadIdx.x;               // 0..63
    const bool hi = lane >= 32;

    const v4f* __restrict__ xi = reinterpret_cast<const v4f*>(x) + img * 4096 + lane;
    v4f* __restrict__ oi       = reinterpret_cast<v4f*>(out)     + img * 4096 + lane;

    // 13/16 of images cacheable (218 MB hot set < 256 MiB L3), 3/16 streamed.
    if ((img & 15) < 13) {
        process_image<false>(xi, oi, lane, hi);
    } else {
        process_image<true>(xi, oi, lane, hi);
    }
}

extern "C" void kernel_launch(void* const* d_in, const int* in_sizes, int n_in,
                              void* d_out, int out_size, void* d_ws, size_t ws_size,
                              hipStream_t stream) {
    const float* x = (const float*)d_in[0];
    float* out = (float*)d_out;

    dim3 grid(16 * 256);   // one wave per (b,c) image
    dim3 block(64);
    BottomRightPool_54357106098213_kernel<<<grid, block, 0, stream>>>(x, out);
}

// Round 10
// 84.650 us; speedup vs baseline: 1.2178x; 1.2178x over previous
//
#include <hip/hip_runtime.h>
#include <cfloat>

// BottomRightPool: out[b,c,i,j] = max(x[b,c,:i+1,:j+1])
//                = cummax over H then cummax over W.
//
// Formulation: out[i] = max(out[i-1], rowscan(x[i])) per column.
// One wave per 128x128 fp32 image (4096 waves). float4 per lane ->
// one 1 KiB instruction covers TWO rows: lanes 0..31 hold row 2k
// (4 cols/lane), lanes 32..63 hold row 2k+1.
//
// Cache policy (best, R6): loads PLAIN (cacheable) -> input reaches the
// deterministic ~50% Infinity-Cache hit steady state across graph
// replays (FETCH == I/2 exactly); stores NONTEMPORAL. R7 (sc0 sc1 nt
// asm stores) and R8 (NT-load partitioning) proved the MALL allocation
// policy is not instruction-steerable: R7 null, R8 -19us. At FETCH=I/2
// the kernel runs at ~6.4 TB/s of logical (L2<->MALL fabric) traffic =
// the measured copy ceiling -> fabric roofline.

typedef float v4f __attribute__((ext_vector_type(4)));

__global__ __launch_bounds__(64)
void BottomRightPool_54357106098213_kernel(const float* __restrict__ x,
                                           float* __restrict__ out) {
    const size_t img = blockIdx.x;              // b*256 + c
    const int lane = threadIdx.x;               // 0..63
    const bool hi = lane >= 32;                 // hi half owns the odd row

    const v4f* __restrict__ xi = reinterpret_cast<const v4f*>(x) + img * 4096 + lane;
    v4f* __restrict__ oi       = reinterpret_cast<v4f*>(out)     + img * 4096 + lane;

    // Running column max for this lane's 4 columns (cols 4*(lane&31)..+3),
    // replicated identically in both wave halves.
    float cm0 = -FLT_MAX, cm1 = -FLT_MAX, cm2 = -FLT_MAX, cm3 = -FLT_MAX;

    #pragma unroll 4
    for (int k = 0; k < 64; ++k) {              // k covers rows 2k, 2k+1
        v4f v = xi[k * 64];                     // plain cacheable load

        // Per-lane inclusive prefixes over the 4 owned columns.
        float p0 = v.x;
        float p1 = fmaxf(p0, v.y);
        float p2 = fmaxf(p1, v.z);
        float p3 = fmaxf(p2, v.w);

        // 32-lane segmented inclusive max-scan of p3 (self-clamped shfl_up).
        float s = p3;
        s = fmaxf(s, __shfl_up(s, 1, 32));
        s = fmaxf(s, __shfl_up(s, 2, 32));
        s = fmaxf(s, __shfl_up(s, 4, 32));
        s = fmaxf(s, __shfl_up(s, 8, 32));
        s = fmaxf(s, __shfl_up(s, 16, 32));
        // Exclusive across-lane value for this segment.
        float e = __shfl_up(s, 1, 32);
        if ((lane & 31) == 0) e = -FLT_MAX;

        // Rowscan of this row at the 4 owned columns.
        float r0 = fmaxf(e, p0);
        float r1 = fmaxf(e, p1);
        float r2 = fmaxf(e, p2);
        float r3 = s;                            // == max(e, p3)

        // Combined two-row rowscan max (same in both halves).
        float t0 = fmaxf(r0, __shfl_xor(r0, 32));
        float t1 = fmaxf(r1, __shfl_xor(r1, 32));
        float t2 = fmaxf(r2, __shfl_xor(r2, 32));
        float t3 = fmaxf(r3, __shfl_xor(r3, 32));

        // Row 2k   (lanes<32):  out = max(cm, rs_row2k)       = max(cm, r)
        // Row 2k+1 (lanes>=32): out = max(cm, rs_2k, rs_2k+1) = max(cm, t)
        v4f o;
        o.x = fmaxf(cm0, hi ? t0 : r0);
        o.y = fmaxf(cm1, hi ? t1 : r1);
        o.z = fmaxf(cm2, hi ? t2 : r2);
        o.w = fmaxf(cm3, hi ? t3 : r3);

        cm0 = fmaxf(cm0, t0);
        cm1 = fmaxf(cm1, t1);
        cm2 = fmaxf(cm2, t2);
        cm3 = fmaxf(cm3, t3);

        __builtin_nontemporal_store(o, &oi[k * 64]);  // NT: keep output out of L2
    }
}

extern "C" void kernel_launch(void* const* d_in, const int* in_sizes, int n_in,
                              void* d_out, int out_size, void* d_ws, size_t ws_size,
                              hipStream_t stream) {
    const float* x = (const float*)d_in[0];
    float* out = (float*)d_out;

    dim3 grid(16 * 256);   // one wave per (b,c) image
    dim3 block(64);
    BottomRightPool_54357106098213_kernel<<<grid, block, 0, stream>>>(x, out);
}